// Round 10
// baseline (129.844 us; speedup 1.0000x reference)
//
#include <hip/hip_runtime.h>
#include <hip/hip_bf16.h>
#include <hip/hip_fp16.h>
#include <math.h>

#define B_  4
#define S_  4096
#define D_  1024
#define M_  (B_ * S_)   // 16384 rows
#define K_  D_          // 1024 reduction
#define L_  32          // scan chunk length
#define NC_ (S_ / L_)   // 128 chunks per sequence
#define NKT 32          // K_/32 K-tiles (BK=32)

typedef __attribute__((ext_vector_type(8))) short          bf16x8;
typedef __attribute__((ext_vector_type(8))) unsigned short u16x8;
typedef __attribute__((ext_vector_type(4))) float          f32x4;

__device__ __forceinline__ unsigned short f2bf(float f) {
    union { __hip_bfloat16 h; unsigned short u; } cv;
    cv.h = __float2bfloat16(f);
    return cv.u;
}

__device__ __forceinline__ float fast_rcp(float x) {
#if __has_builtin(__builtin_amdgcn_rcpf)
    return __builtin_amdgcn_rcpf(x);
#else
    return 1.0f / x;
#endif
}

__device__ __forceinline__ void stage16(const unsigned short* src, char* dst) {
    __builtin_amdgcn_global_load_lds(
        (const __attribute__((address_space(1))) unsigned int*)src,
        (__attribute__((address_space(3))) unsigned int*)dst, 16, 0, 0);
}

// ---------------------------------------------------------------------------
// Kernel 0: fp32 -> bf16 pre-convert, x and W in ONE launch
// ---------------------------------------------------------------------------
__global__ __launch_bounds__(256) void to_bf16_both(
    const float* __restrict__ x, const float* __restrict__ W,
    unsigned short* __restrict__ xb, unsigned short* __restrict__ Wb,
    int n8x, int n8w)
{
    int i = blockIdx.x * 256 + threadIdx.x;
    const float* src;
    unsigned short* dst;
    int j;
    if (i < n8x) { src = x; dst = xb; j = i; }
    else {
        j = i - n8x;
        if (j >= n8w) return;
        src = W; dst = Wb;
    }
    const float4* p = (const float4*)src + (size_t)j * 2;
    float4 a = p[0], b = p[1];
    u16x8 o;
    o[0] = f2bf(a.x); o[1] = f2bf(a.y); o[2] = f2bf(a.z); o[3] = f2bf(a.w);
    o[4] = f2bf(b.x); o[5] = f2bf(b.y); o[6] = f2bf(b.z); o[7] = f2bf(b.w);
    *(u16x8*)(dst + (size_t)j * 8) = o;
}

// ---------------------------------------------------------------------------
// Kernel 1: bf16 MFMA GEMM, 2-blocks/CU barrier-decoupled variant.
// BM=128, BN=128d x {h,g} = 256 cols, BK=32, 4 waves (2m x 2n), wave tile
// 64m x 128c (acc[4][8]). LDS = 3 bufs x 24KB = 72KB -> TWO independent
// blocks per CU (144 <= 160KB): when one block stalls at barrier/vmcnt the
// other feeds the MFMA pipe (the axis untested in rounds 4-9, all 1 blk/CU).
// Buf: A[128][32]bf16 @0 (8KB), B @8192 (16KB: rows 0-127 hidden W,
// 128-255 gate). Rows 64B, swizzle involution slot^=(row>>1)&3 on BOTH
// stage-source and read (0 conflicts, rounds 3-9).
// Schedule/tile: 2 phases {reads, stage t+2 part, bar, lgk0, 16 MFMA
// setprio, bar}; counted vmcnt(6) at tile end (never 0 until epilogue).
// Epilogue: linear-domain pointwise + cvb half2(c,v) + fused chunk-(C,V)
// compose (r-fold -> shfl_xor 16/32 -> mi-pair) -> CVagg (round-8-verified).
// ---------------------------------------------------------------------------
__global__ __launch_bounds__(256, 2) void gemm_pointwise(
    const unsigned short* __restrict__ xb, const unsigned short* __restrict__ Wb,
    __half2* __restrict__ cvb, float2* __restrict__ CVagg)
{
    __shared__ char lds[73728];   // 3 bufs x 24KB

    const int th   = threadIdx.x;
    const int lane = th & 63;
    const int wave = th >> 6;      // 0..3
    const int wm = wave >> 1;      // 0..1 -> m offset 0/64
    const int wn = wave & 1;       // 0..1 -> d offset 0/64

    const int wg  = blockIdx.x;                     // 1024 wgs, 8 XCDs
    const int swz = (wg & 7) * 128 + (wg >> 3);     // bijective XCD swizzle
    const int m0 = (swz >> 3) * 128;
    const int d0 = (swz & 7) * 128;

    f32x4 acc[4][8];
#pragma unroll
    for (int i = 0; i < 4; ++i)
#pragma unroll
        for (int j = 0; j < 8; ++j)
            acc[i][j] = (f32x4){0.f, 0.f, 0.f, 0.f};

    // staging: 256 thr x 16B = 4KB = 64 rows of 64B per stage16 call
    const int srow = th >> 2;                               // 0..63
    const int scol = (((th & 3) ^ ((th >> 3) & 3)) * 8);    // pre-swizzled col
    const unsigned short* srcA  = xb + (size_t)(m0 + srow)      * K_ + scol;
    const unsigned short* srcBh = Wb + (size_t)(d0 + srow)      * K_ + scol;
    const unsigned short* srcBg = Wb + (size_t)(D_ + d0 + srow) * K_ + scol;
    char* const wuo = lds + wave * 1024;   // wave-uniform LDS dest base

    const int lr = lane & 15;
    const int lq = lane >> 4;
    const int lkb = ((lq ^ ((lr >> 1) & 3)) * 16);            // swizzled slot
    const int aoffb = (wm * 64 + lr) * 64 + lkb;              // A frag base
    const int boffh = 8192 + (wn * 64 + lr) * 64 + lkb;       // B hidden base
    const int boffg = boffh + 8192;                           // B gate (+128 rows)

    bf16x8 Af[4], Bf[8];

#define BAR()  asm volatile("s_barrier" ::: "memory")
#define LGK0() asm volatile("s_waitcnt lgkmcnt(0)" ::: "memory")
#define VMW6() asm volatile("s_waitcnt vmcnt(6)" ::: "memory")
#define VMW0() asm volatile("s_waitcnt vmcnt(0)" ::: "memory")

#define STAGE_AH(tt, q) do { const int ko_ = (tt) * 32;                   \
    stage16(srcA  + ko_,            (q));                                 \
    stage16(srcA  + 64 * K_ + ko_,  (q) + 4096);                          \
    stage16(srcBh + ko_,            (q) + 8192);                          \
    stage16(srcBh + 64 * K_ + ko_,  (q) + 12288); } while (0)
#define STAGE_G(tt, q) do { const int ko_ = (tt) * 32;                    \
    stage16(srcBg + ko_,            (q) + 16384);                         \
    stage16(srcBg + 64 * K_ + ko_,  (q) + 20480); } while (0)

// phase A: A frags + hidden-B frags -> 16 MFMA (nj 0..3)
// phase B: gate-B frags -> 16 MFMA (nj 4..7), A reused from registers
#define TILEBODY(T, P0, Q2, PRE, WAITOP) do {                             \
    _Pragma("unroll")                                                     \
    for (int i_ = 0; i_ < 4; ++i_)                                        \
        Af[i_] = *(const bf16x8*)((P0) + aoffb + i_ * 1024);              \
    _Pragma("unroll")                                                     \
    for (int j_ = 0; j_ < 4; ++j_)                                        \
        Bf[j_] = *(const bf16x8*)((P0) + boffh + j_ * 1024);              \
    if (PRE) { STAGE_AH((T) + 2, (Q2)); }                                 \
    BAR(); LGK0();                                                        \
    __builtin_amdgcn_s_setprio(1);                                        \
    _Pragma("unroll")                                                     \
    for (int i_ = 0; i_ < 4; ++i_)                                        \
        _Pragma("unroll")                                                 \
        for (int j_ = 0; j_ < 4; ++j_)                                    \
            acc[i_][j_] = __builtin_amdgcn_mfma_f32_16x16x32_bf16(        \
                Af[i_], Bf[j_], acc[i_][j_], 0, 0, 0);                    \
    __builtin_amdgcn_s_setprio(0);                                        \
    BAR();                                                                \
    _Pragma("unroll")                                                     \
    for (int j_ = 0; j_ < 4; ++j_)                                        \
        Bf[4 + j_] = *(const bf16x8*)((P0) + boffg + j_ * 1024);          \
    if (PRE) { STAGE_G((T) + 2, (Q2)); }                                  \
    BAR(); LGK0();                                                        \
    __builtin_amdgcn_s_setprio(1);                                        \
    _Pragma("unroll")                                                     \
    for (int i_ = 0; i_ < 4; ++i_)                                        \
        _Pragma("unroll")                                                 \
        for (int j_ = 0; j_ < 4; ++j_)                                    \
            acc[i_][4 + j_] = __builtin_amdgcn_mfma_f32_16x16x32_bf16(    \
                Af[i_], Bf[4 + j_], acc[i_][4 + j_], 0, 0, 0);            \
    __builtin_amdgcn_s_setprio(0);                                        \
    WAITOP;                                                               \
    BAR();                                                                \
  } while (0)

    // rotating buffer pointers (named, never runtime-indexed — rule #20)
    const char* p0 = lds;                 // compute buf (read side)
    const char* p1 = lds + 24576;
    const char* p2 = lds + 49152;
    char* q0 = wuo;                       // stage dests (wave-uniform)
    char* q1 = wuo + 24576;
    char* q2 = wuo + 49152;

    // prologue: stage tiles 0,1 (12 loads), wait tile 0 only (counted)
    STAGE_AH(0, q0); STAGE_G(0, q0);
    STAGE_AH(1, q1); STAGE_G(1, q1);
    VMW6();
    BAR();

#pragma unroll 1
    for (int t = 0; t < NKT - 2; ++t) {   // t = 0..29, stage t+2
        TILEBODY(t, p0, q2, 1, VMW6());
        const char* tp = p0; p0 = p1; p1 = p2; p2 = tp;
        char* tq = q0; q0 = q1; q1 = q2; q2 = tq;
    }
    TILEBODY(NKT - 2, p0, q2, 0, VMW0()); // t=30: drain tile 31's loads
    { const char* tp = p0; p0 = p1; p1 = p2; p2 = tp; }
    TILEBODY(NKT - 1, p0, q2, 0, (void)0);  // t=31

#undef TILEBODY
#undef STAGE_AH
#undef STAGE_G
#undef BAR
#undef LGK0
#undef VMW6
#undef VMW0

    // ---- epilogue: pointwise + cvb store + fused chunk-(C,V) reduction ----
    // C/D: col = lane&15 (d), row = lq*4 + reg (m). Lane rows for frag mi:
    // wm*64 + mi*16 + lq*4 + {0..3}. Chunk (32 rows) = mi pair; compose
    // r-fold -> lq-compose (shfl_xor 16,32) -> mi-pair; write at lq==0.
#pragma unroll
    for (int mp = 0; mp < 2; ++mp) {          // mi pair (2mp, 2mp+1)
        float C16[2][4], V16[2][4];
#pragma unroll
        for (int hf = 0; hf < 2; ++hf) {
            const int mi = mp * 2 + hf;
#pragma unroll
            for (int nj = 0; nj < 4; ++nj) {
                float C4 = 1.0f, V4 = 0.0f;
                const int d = d0 + wn * 64 + nj * 16 + lr;
#pragma unroll
                for (int r = 0; r < 4; ++r) {
                    int m = m0 + wm * 64 + mi * 16 + lq * 4 + r;
                    float h = acc[mi][nj][r];         // hidden
                    float g = acc[mi][nj + 4][r];     // gate, same d
                    float eg  = __expf(g);
                    float c   = fast_rcp(1.0f + eg);  // sigma(-g)
                    float z   = eg * c;               // sigma(g)
                    float enh = __expf(-h);
                    float sh  = fast_rcp(1.0f + enh); // sigma(h)
                    float gh  = (h >= 0.0f) ? (h + 0.5f) : sh;
                    float v   = z * gh;
                    cvb[(size_t)m * D_ + d] = __floats2half2_rn(c, v);
                    V4 = fmaf(c, V4, v);              // compose ascending r
                    C4 *= c;
                }
                // lq-compose (rows base+lq*4, ascending lq):
                float Ca = __shfl_xor(C4, 16), Va = __shfl_xor(V4, 16);
                float Clo = (lq & 1) ? Ca : C4, Vlo = (lq & 1) ? Va : V4;
                float Chi = (lq & 1) ? C4 : Ca, Vhi = (lq & 1) ? V4 : Va;
                float C2 = Clo * Chi, V2 = fmaf(Chi, Vlo, Vhi);
                float Cb = __shfl_xor(C2, 32), Vb = __shfl_xor(V2, 32);
                float Cl2 = (lq & 2) ? Cb : C2, Vl2 = (lq & 2) ? Vb : V2;
                float Ch2 = (lq & 2) ? C2 : Cb, Vh2 = (lq & 2) ? V2 : Vb;
                C16[hf][nj] = Cl2 * Ch2;
                V16[hf][nj] = fmaf(Ch2, Vl2, Vh2);
            }
        }
        if (lq == 0) {
            const int chunkg = (m0 + wm * 64 + mp * 32) >> 5;  // global chunk
#pragma unroll
            for (int nj = 0; nj < 4; ++nj) {
                float C32 = C16[0][nj] * C16[1][nj];
                float V32 = fmaf(C16[1][nj], V16[0][nj], V16[1][nj]);
                const int d = d0 + wn * 64 + nj * 16 + lr;
                float2 st; st.x = C32; st.y = V32;
                CVagg[(size_t)chunkg * D_ + d] = st;
            }
        }
    }
}

// ---------------------------------------------------------------------------
// Kernel 3: scan across chunks (128 FMA steps, tiny). P[c] = h at chunk entry.
// ---------------------------------------------------------------------------
__global__ __launch_bounds__(256) void chunk_scan(
    const float2* __restrict__ CVagg, float* __restrict__ P)
{
    const int d = blockIdx.x * 256 + threadIdx.x;
    const int b = blockIdx.z;
    float h = 0.0f;
    for (int c = 0; c < NC_; ++c) {
        size_t o = ((size_t)b * NC_ + c) * D_ + d;
        P[o] = h;
        float2 cv = CVagg[o];
        h = fmaf(cv.x, h, cv.y);
    }
}

// ---------------------------------------------------------------------------
// Kernel 4: apply — h = fma(c, h, v) from chunk-entry prefix; write fp32 out.
// ---------------------------------------------------------------------------
__global__ __launch_bounds__(256) void chunk_apply(
    const unsigned int* __restrict__ cvw, const float* __restrict__ P,
    float* __restrict__ out)
{
    const int d = (blockIdx.x * 256 + threadIdx.x) * 2;
    const int c = blockIdx.y;
    const int b = blockIdx.z;
    size_t base = ((size_t)(b * S_ + c * L_)) * D_ + d;
    float2 h2 = *(const float2*)(P + ((size_t)b * NC_ + c) * D_ + d);
    float h0 = h2.x, h1 = h2.y;
    for (int s = 0; s < L_; ++s) {
        uint2 u = *(const uint2*)(cvw + base + (size_t)s * D_);
        float2 p0 = __half22float2(*(const __half2*)&u.x);
        float2 p1 = __half22float2(*(const __half2*)&u.y);
        h0 = fmaf(p0.x, h0, p0.y);
        h1 = fmaf(p1.x, h1, p1.y);
        float2 o2 = {h0, h1};
        *(float2*)(out + base + (size_t)s * D_) = o2;
    }
}

extern "C" void kernel_launch(void* const* d_in, const int* in_sizes, int n_in,
                              void* d_out, int out_size, void* d_ws, size_t ws_size,
                              hipStream_t stream) {
    const float* x = (const float*)d_in[0];   // [B,S,D] fp32
    const float* W = (const float*)d_in[1];   // [2D,D] fp32
    float* out = (float*)d_out;               // [B,S,D] fp32

    float2* CVagg = (float2*)d_ws;                             // B*NC*D float2
    float*  P     = (float*)(CVagg + (size_t)B_ * NC_ * D_);
    __half2* cvb  = (__half2*)(P + (size_t)B_ * NC_ * D_);     // M*D half2
    unsigned short* xb = (unsigned short*)(cvb + (size_t)M_ * D_);  // M*K bf16
    unsigned short* Wb = xb + (size_t)M_ * K_;                      // 2D*K bf16

    const int n8x = M_ * K_ / 8;          // 2,097,152
    const int n8w = 2 * D_ * K_ / 8;      // 262,144
    to_bf16_both<<<(n8x + n8w + 255) / 256, 256, 0, stream>>>(x, W, xb, Wb, n8x, n8w);

    // 1024 wgs: 128 m-tiles x 8 d-tiles, XCD-swizzled in-kernel
    gemm_pointwise<<<1024, 256, 0, stream>>>(xb, Wb, cvb, CVagg);

    dim3 g3(D_ / 256, 1, B_);      // 4 x 1 x 4
    chunk_scan<<<g3, 256, 0, stream>>>(CVagg, P);

    dim3 g2(D_ / 512, NC_, B_);    // 2 x 128 x 4
    chunk_apply<<<g2, 256, 0, stream>>>((const unsigned int*)cvb, P, out);
}